// Round 14
// baseline (136.173 us; speedup 1.0000x reference)
//
#include <hip/hip_runtime.h>

#define NB 1024
#define NE 8

__device__ __forceinline__ float relu6f(float v) { return fminf(fmaxf(v, 0.0f), 6.0f); }

// ---- pure-DPP wave64 reductions ----
template <int CTRL>
__device__ __forceinline__ float dpp0(float x) {
    return __builtin_bit_cast(float,
        __builtin_amdgcn_update_dpp(0, __builtin_bit_cast(int, x), CTRL, 0xF, 0xF, false));
}
__device__ __forceinline__ float wmax63(float x) {   // nonneg inputs only
    x = fmaxf(x, dpp0<0x121>(x));
    x = fmaxf(x, dpp0<0x122>(x));
    x = fmaxf(x, dpp0<0x124>(x));
    x = fmaxf(x, dpp0<0x128>(x));
    x = fmaxf(x, dpp0<0x142>(x));
    x = fmaxf(x, dpp0<0x143>(x));
    return x;
}
__device__ __forceinline__ float wsum63(float x) {
    x += dpp0<0x121>(x);
    x += dpp0<0x122>(x);
    x += dpp0<0x124>(x);
    x += dpp0<0x128>(x);
    x += dpp0<0x142>(x);
    x += dpp0<0x143>(x);
    return x;
}

// HOT PATH: 8-value wave64 sum, fused v_add_f32_dpp, stage-major interleave
// (dependent ops 8 apart -> DPP hazard covered). Result valid in lanes 48..63.
#define DPP_ROW(OPND, CTRL) \
    "v_add_f32_dpp " OPND ", " OPND ", " OPND " " CTRL \
    " row_mask:0xf bank_mask:0xf bound_ctrl:0\n\t"
#define DPP_STAGE(CTRL) \
    DPP_ROW("%0", CTRL) DPP_ROW("%1", CTRL) DPP_ROW("%2", CTRL) DPP_ROW("%3", CTRL) \
    DPP_ROW("%4", CTRL) DPP_ROW("%5", CTRL) DPP_ROW("%6", CTRL) DPP_ROW("%7", CTRL)

__device__ __forceinline__ void wsum63x8(float p[8]) {
    asm volatile(
        "s_nop 1\n\t"
        DPP_STAGE("row_ror:1")
        DPP_STAGE("row_ror:2")
        DPP_STAGE("row_ror:4")
        DPP_STAGE("row_ror:8")
        DPP_STAGE("row_bcast:15")
        DPP_STAGE("row_bcast:31")
        : "+v"(p[0]), "+v"(p[1]), "+v"(p[2]), "+v"(p[3]),
          "+v"(p[4]), "+v"(p[5]), "+v"(p[6]), "+v"(p[7]));
}

// ---------------- Kernel A: router conv + softmax (R11, unchanged) ---------
__global__ __launch_bounds__(256) void router_kernel(
    const float* __restrict__ x, const float* __restrict__ rw,
    const float* __restrict__ rb, float* __restrict__ ss)
{
    __shared__ float rw_l[384];
    __shared__ float red[4][8];
    int b = blockIdx.x, t = threadIdx.x;
    for (int i = t; i < 384; i += 256) rw_l[i] = rw[i];
    __syncthreads();
    float acc[NE];
#pragma unroll
    for (int e = 0; e < NE; ++e) acc[e] = 0.f;
    const float* xb = x + b * 3072;
    for (int idx = t; idx < 3072; idx += 256) {
        float xv = xb[idx];
        int c = idx >> 10, rem = idx & 1023;
        int i = rem >> 5, j = rem & 31;
        int wb = c * 16 + (i & 3) * 4 + (j & 3);
#pragma unroll
        for (int e = 0; e < NE; ++e) acc[e] += xv * rw_l[e * 48 + wb];
    }
    wsum63x8(acc);
    int lane = t & 63, wave = t >> 6;
    if (lane == 63) {
#pragma unroll
        for (int e = 0; e < NE; ++e) red[wave][e] = acc[e];
    }
    __syncthreads();
    if (t == 0) {
        float s[NE], m = -1e30f;
#pragma unroll
        for (int e = 0; e < NE; ++e) {
            s[e] = red[0][e] + red[1][e] + red[2][e] + red[3][e] + rb[e];
            m = fmaxf(m, s[e]);
        }
        float xs = 0.f, ex[NE];
#pragma unroll
        for (int e = 0; e < NE; ++e) { ex[e] = expf(s[e] - m); xs += ex[e]; }
#pragma unroll
        for (int e = 0; e < NE; ++e) ss[b * 8 + e] = ex[e] / xs;
    }
}

// ---------------- Kernel B: OT solver (R11/R13, unchanged — at floor) ------
// 175 serial reduce->barrier->readback rounds ≈ 556cy each ≈ 97us; VALU 52%
// on the busy CU, rest is dependency stall. Verified model == measurement.
// G_n = I8; G_m == I (off-diag d~5400 -> exp underflows), so C_eff = C - pi.
__global__ __launch_bounds__(256, 2) void solver_kernel(
    const float* __restrict__ ss_g, float* __restrict__ gate_ws,
    int* __restrict__ idx_ws, float* __restrict__ sel0,
    float* __restrict__ loss_out, float* __restrict__ mcnt_out)
{
    __shared__ float sst[8192];                      // ss transposed: [e*1024+col]
    __shared__ __align__(16) float red[2][4][8];     // [parity][wave][e]
    __shared__ float redm[2][4];                     // [parity][wave] max partials
    __shared__ __align__(16) float cnt_sh[4][8], dp_sh[4][8];

    int t = threadIdx.x;
    int l = t & 63, w = t >> 6;

    float mx = 0.f;
    for (int i = t; i < 2048; i += 256) {
        float4 s4 = ((const float4*)ss_g)[i];
        int col = i >> 1, e0 = (i & 1) * 4;
        sst[(e0 + 0) * 1024 + col] = s4.x;
        sst[(e0 + 1) * 1024 + col] = s4.y;
        sst[(e0 + 2) * 1024 + col] = s4.z;
        sst[(e0 + 3) * 1024 + col] = s4.w;
        mx = fmaxf(mx, fmaxf(fmaxf(s4.x, s4.y), fmaxf(s4.z, s4.w)));
    }
    mx = wmax63(mx);
    if (l == 63) redm[0][w] = mx;
    __syncthreads();
    float gm = fmaxf(fmaxf(redm[0][0], redm[0][1]), fmaxf(redm[0][2], redm[0][3]));
    float ninv0 = -__builtin_amdgcn_rcpf(gm + 1e-9f);   // c = ss * ninv0

    int col0 = w * 256 + l;
    float c[4][8], k[4][8], v[4], u[8], p[8];
#pragma unroll
    for (int q = 0; q < 4; ++q) {
        v[q] = 1.f;
#pragma unroll
        for (int e = 0; e < 8; ++e) {
            c[q][e] = sst[e * 1024 + col0 + q * 64] * ninv0;  // once-scaled C
            k[q][e] = 1.f;
        }
    }
#pragma unroll
    for (int e = 0; e < 8; ++e) u[e] = 0.125f;   // u*k*v == pi0 == 0.125

    for (int outer = 0; outer < 25; ++outer) {
        int sm = (outer + 1) & 1;
        float lm = 0.f;
#pragma unroll
        for (int q = 0; q < 4; ++q)
#pragma unroll
            for (int e = 0; e < 8; ++e) {
                float ce = c[q][e] - u[e] * k[q][e] * v[q];
                k[q][e] = ce;
                lm = fmaxf(lm, fabsf(ce));
            }
        lm = wmax63(lm);
        if (l == 63) redm[sm][w] = lm;
        __syncthreads();
        float gmx = fmaxf(fmaxf(redm[sm][0], redm[sm][1]),
                          fmaxf(redm[sm][2], redm[sm][3]));
        float scl = -10.f * __builtin_amdgcn_rcpf(gmx + 1e-9f);  // -(1/sden)/LDA

        // exp pass fused with p0 = K @ 1
#pragma unroll
        for (int e = 0; e < 8; ++e) p[e] = 0.f;
#pragma unroll
        for (int q = 0; q < 4; ++q)
#pragma unroll
            for (int e = 0; e < 8; ++e) {
                float kk = __expf(k[q][e] * scl);
                k[q][e] = kk;
                p[e] += kk;
            }

        for (int it = 0; it < 6; ++it) {          // 5 full (u,v) + final u
            int s = it & 1;
            wsum63x8(p);
            if (l == 63) {
                *(float4*)&red[s][w][0] = make_float4(p[0], p[1], p[2], p[3]);
                *(float4*)&red[s][w][4] = make_float4(p[4], p[5], p[6], p[7]);
            }
            __syncthreads();
            float4 t00 = *(const float4*)&red[s][0][0];
            float4 t01 = *(const float4*)&red[s][0][4];
            float4 t10 = *(const float4*)&red[s][1][0];
            float4 t11 = *(const float4*)&red[s][1][4];
            float4 t20 = *(const float4*)&red[s][2][0];
            float4 t21 = *(const float4*)&red[s][2][4];
            float4 t30 = *(const float4*)&red[s][3][0];
            float4 t31 = *(const float4*)&red[s][3][4];
            u[0] = 128.f * __builtin_amdgcn_rcpf((t00.x + t10.x) + (t20.x + t30.x) + 1e-9f);
            u[1] = 128.f * __builtin_amdgcn_rcpf((t00.y + t10.y) + (t20.y + t30.y) + 1e-9f);
            u[2] = 128.f * __builtin_amdgcn_rcpf((t00.z + t10.z) + (t20.z + t30.z) + 1e-9f);
            u[3] = 128.f * __builtin_amdgcn_rcpf((t00.w + t10.w) + (t20.w + t30.w) + 1e-9f);
            u[4] = 128.f * __builtin_amdgcn_rcpf((t01.x + t11.x) + (t21.x + t31.x) + 1e-9f);
            u[5] = 128.f * __builtin_amdgcn_rcpf((t01.y + t11.y) + (t21.y + t31.y) + 1e-9f);
            u[6] = 128.f * __builtin_amdgcn_rcpf((t01.z + t11.z) + (t21.z + t31.z) + 1e-9f);
            u[7] = 128.f * __builtin_amdgcn_rcpf((t01.w + t11.w) + (t21.w + t31.w) + 1e-9f);
            if (it < 5) {
#pragma unroll
                for (int e = 0; e < 8; ++e) p[e] = 0.f;
#pragma unroll
                for (int q = 0; q < 4; ++q) {
                    float cs = 0.f;
#pragma unroll
                    for (int e = 0; e < 8; ++e) cs = fmaf(k[q][e], u[e], cs);
                    float vq = __builtin_amdgcn_rcpf(cs + 1e-9f);
                    v[q] = vq;
#pragma unroll
                    for (int e = 0; e < 8; ++e) p[e] = fmaf(k[q][e], vq, p[e]);
                }
            }
        }
    }

    // ---- epilogue: argmax / gate / select0 / counts / loss ----
    float cnt[8], dp[8];
#pragma unroll
    for (int e = 0; e < 8; ++e) { cnt[e] = 0.f; dp[e] = 0.f; }
#pragma unroll
    for (int q = 0; q < 4; ++q) {
        int col = col0 + q * 64;
        float pv[8];
#pragma unroll
        for (int e = 0; e < 8; ++e) pv[e] = u[e] * k[q][e] * v[q];
        int i = 0; float m = pv[0];
#pragma unroll
        for (int e = 1; e < 8; ++e) { if (pv[e] > m) { m = pv[e]; i = e; } }
        float g = 0.f;
        float se[8];
#pragma unroll
        for (int e = 0; e < 8; ++e) {
            float sv = sst[e * 1024 + col];
            dp[e] += sv;
            if (i == e) g = sv;
        }
#pragma unroll
        for (int e = 0; e < 8; ++e) {
            se[e] = (e == i && g != 0.f) ? 1.f : 0.f;
            cnt[e] += (e == i) ? 1.f : 0.f;
        }
        idx_ws[col] = i;
        gate_ws[col] = g;
        *(float4*)&sel0[col * 8]     = make_float4(se[0], se[1], se[2], se[3]);
        *(float4*)&sel0[col * 8 + 4] = make_float4(se[4], se[5], se[6], se[7]);
    }
#pragma unroll
    for (int e = 0; e < 8; ++e) { cnt[e] = wsum63(cnt[e]); dp[e] = wsum63(dp[e]); }
    if (l == 63) {
#pragma unroll
        for (int e = 0; e < 8; ++e) { cnt_sh[w][e] = cnt[e]; dp_sh[w][e] = dp[e]; }
    }
    __syncthreads();
    if (t == 0) {
        float loss = 0.f;
#pragma unroll
        for (int e = 0; e < 8; ++e) {
            float ce2 = cnt_sh[0][e] + cnt_sh[1][e] + cnt_sh[2][e] + cnt_sh[3][e];
            float de2 = dp_sh[0][e] + dp_sh[1][e] + dp_sh[2][e] + dp_sh[3][e];
            loss += (de2 * (1.f / 1024.f)) * (ce2 * (1.f / 1024.f));
            mcnt_out[e] = ce2;
        }
        loss_out[0] = loss * 8.f;
    }
}

// ---------------- Kernel C: per-sample fused expert forward ----------------
// R14: xl stride 35->36 (row base = 144B = 9x16B -> 16B-aligned) so conv1's
// xreg[18] loads become 4x ds_read_b128 + 2x b32 (was 18x b32; 3x fewer LDS
// issues, ~1300cy/block). Overhang zeroing hoisted out of the group loop
// (conv1 never writes row/col 32 -> loop-invariant). Arithmetic order
// unchanged -> output bit-identical to R13.
__global__ __launch_bounds__(256, 2) void expert_kernel(
    const float* __restrict__ x,
    const float* __restrict__ w1g, const float* __restrict__ b1g,
    const float* __restrict__ wdg, const float* __restrict__ bdg,
    const float* __restrict__ wpg, const float* __restrict__ bpg,
    const float* __restrict__ wfg, const float* __restrict__ bfg,
    const int* __restrict__ idx_ws, const float* __restrict__ gate_ws,
    float* __restrict__ out)
{
    __shared__ __align__(16) float xl[3][34][36];    // stride 36: rows 16B-aligned
    __shared__ float h1[8][33][33];   // 8-channel group; row/col 32 zeroed once
    __shared__ __align__(16) float h2q[4][256][4];   // [c>>2][point][c&3]
    __shared__ float w1_l[432];
    __shared__ float wd_l[144];
    __shared__ float wp_l[512];
    __shared__ float wf_l[320];
    __shared__ float b1_l[16], bd_l[16], bp_l[32], bf_l[10];
    __shared__ __align__(16) float pooled[32];

    int b = blockIdx.x, t = threadIdx.x;
    int l = t & 63;
    int e = idx_ws[b];
    float gate = gate_ws[b];

    float* xz = &xl[0][0][0];
    for (int i = t; i < 3 * 34 * 36; i += 256) xz[i] = 0.f;
    for (int i = t; i < 432; i += 256) w1_l[i] = w1g[e * 432 + i];
    if (t < 144) wd_l[t] = wdg[e * 144 + t];
    for (int i = t; i < 512; i += 256) wp_l[i] = wpg[e * 512 + i];
    for (int i = t; i < 320; i += 256) wf_l[i] = wfg[e * 320 + i];
    if (t < 16) b1_l[t] = b1g[e * 16 + t];
    if (t < 16) bd_l[t] = bdg[e * 16 + t];
    if (t < 32) bp_l[t] = bpg[e * 32 + t];
    if (t < 10) bf_l[t] = bfg[e * 10 + t];
    // h1 stride-2 SAME overhang zeros — loop-invariant, done once here:
    { int cc = t / 33, kk = t % 33; if (cc < 8) h1[cc][32][kk] = 0.f; }
    if (t < 8) { h1[7][32][t + 25] = 0.f; }
    h1[t >> 5][t & 31][32] = 0.f;
    __syncthreads();
    const float* xb = x + b * 3072;
    for (int i = t; i < 3072; i += 256) {
        int c = i >> 10, r = (i >> 5) & 31, j = i & 31;
        xl[c][r + 1][j + 1] = xb[i];
    }
    __syncthreads();

    int ocl = t >> 6;
    int rr = (t >> 1) & 31;
    int jh = t & 1;

    for (int g = 0; g < 2; ++g) {
        int oc0 = g * 8 + ocl * 2;
        float acc[2][16];
#pragma unroll
        for (int kk = 0; kk < 16; ++kk) { acc[0][kk] = b1_l[oc0]; acc[1][kk] = b1_l[oc0 + 1]; }
#pragma unroll
        for (int c = 0; c < 3; ++c) {
#pragma unroll
            for (int di = 0; di < 3; ++di) {
                const float* xr = &xl[c][rr + di][jh * 16];
                float4 f0 = *(const float4*)(xr);
                float4 f1 = *(const float4*)(xr + 4);
                float4 f2 = *(const float4*)(xr + 8);
                float4 f3 = *(const float4*)(xr + 12);
                float xreg[18];
                xreg[0] = f0.x;  xreg[1] = f0.y;  xreg[2] = f0.z;  xreg[3] = f0.w;
                xreg[4] = f1.x;  xreg[5] = f1.y;  xreg[6] = f1.z;  xreg[7] = f1.w;
                xreg[8] = f2.x;  xreg[9] = f2.y;  xreg[10] = f2.z; xreg[11] = f2.w;
                xreg[12] = f3.x; xreg[13] = f3.y; xreg[14] = f3.z; xreg[15] = f3.w;
                xreg[16] = xr[16]; xreg[17] = xr[17];
#pragma unroll
                for (int dj = 0; dj < 3; ++dj) {
                    float w0 = w1_l[oc0 * 27 + c * 9 + di * 3 + dj];
                    float w1 = w1_l[(oc0 + 1) * 27 + c * 9 + di * 3 + dj];
#pragma unroll
                    for (int kk = 0; kk < 16; ++kk) {
                        acc[0][kk] = fmaf(xreg[kk + dj], w0, acc[0][kk]);
                        acc[1][kk] = fmaf(xreg[kk + dj], w1, acc[1][kk]);
                    }
                }
            }
        }
        int lc0 = ocl * 2;
#pragma unroll
        for (int kk = 0; kk < 16; ++kk) {
            h1[lc0][rr][jh * 16 + kk]     = relu6f(acc[0][kk]);
            h1[lc0 + 1][rr][jh * 16 + kk] = relu6f(acc[1][kk]);
        }
        __syncthreads();
        int i2 = t >> 4, j2 = t & 15;
        float dwa[8];
#pragma unroll
        for (int q = 0; q < 8; ++q) {
            float a = bd_l[g * 8 + q];
#pragma unroll
            for (int di = 0; di < 3; ++di) {
#pragma unroll
                for (int dj = 0; dj < 3; ++dj)
                    a = fmaf(h1[q][2 * i2 + di][2 * j2 + dj],
                             wd_l[(g * 8 + q) * 9 + di * 3 + dj], a);
            }
            dwa[q] = relu6f(a);
        }
        *(float4*)&h2q[g * 2 + 0][t][0] = make_float4(dwa[0], dwa[1], dwa[2], dwa[3]);
        *(float4*)&h2q[g * 2 + 1][t][0] = make_float4(dwa[4], dwa[5], dwa[6], dwa[7]);
        __syncthreads();
    }

    // pointwise 16->32 (+bp, relu6) + pool: wave=8 oc, lane=4 pts (stride 64)
    {
        int ocg = t >> 6;
        int pg  = t & 63;
        float hv[4][16];
#pragma unroll
        for (int pt = 0; pt < 4; ++pt) {
            int pp = pg + pt * 64;
            float4 q0 = *(const float4*)&h2q[0][pp][0];
            float4 q1 = *(const float4*)&h2q[1][pp][0];
            float4 q2 = *(const float4*)&h2q[2][pp][0];
            float4 q3 = *(const float4*)&h2q[3][pp][0];
            hv[pt][0] = q0.x;  hv[pt][1] = q0.y;  hv[pt][2] = q0.z;  hv[pt][3] = q0.w;
            hv[pt][4] = q1.x;  hv[pt][5] = q1.y;  hv[pt][6] = q1.z;  hv[pt][7] = q1.w;
            hv[pt][8] = q2.x;  hv[pt][9] = q2.y;  hv[pt][10] = q2.z; hv[pt][11] = q2.w;
            hv[pt][12] = q3.x; hv[pt][13] = q3.y; hv[pt][14] = q3.z; hv[pt][15] = q3.w;
        }
        float pool[8];
#pragma unroll
        for (int o = 0; o < 8; ++o) {
            int oc = ocg * 8 + o;
            float a0 = bp_l[oc], a1 = a0, a2 = a0, a3 = a0;
#pragma unroll
            for (int c = 0; c < 16; ++c) {
                float wv = wp_l[oc * 16 + c];
                a0 = fmaf(hv[0][c], wv, a0);
                a1 = fmaf(hv[1][c], wv, a1);
                a2 = fmaf(hv[2][c], wv, a2);
                a3 = fmaf(hv[3][c], wv, a3);
            }
            pool[o] = (relu6f(a0) + relu6f(a1)) + (relu6f(a2) + relu6f(a3));
        }
        wsum63x8(pool);
        if (l == 63) {
            *(float4*)&pooled[ocg * 8]     = make_float4(pool[0], pool[1], pool[2], pool[3]);
            *(float4*)&pooled[ocg * 8 + 4] = make_float4(pool[4], pool[5], pool[6], pool[7]);
        }
    }
    __syncthreads();
    if (t < 10) {
        float o = bf_l[t];
#pragma unroll
        for (int c = 0; c < 32; ++c)
            o = fmaf(pooled[c] * (1.0f / 256.0f), wf_l[t * 32 + c], o);
        out[b * 10 + t] = gate * o;
    }
}

extern "C" void kernel_launch(void* const* d_in, const int* in_sizes, int n_in,
                              void* d_out, int out_size, void* d_ws, size_t ws_size,
                              hipStream_t stream) {
    const float* x  = (const float*)d_in[0];
    const float* rw = (const float*)d_in[1];
    const float* rb = (const float*)d_in[2];
    const float* w1 = (const float*)d_in[3];
    const float* b1 = (const float*)d_in[4];
    const float* wd = (const float*)d_in[5];
    const float* bd = (const float*)d_in[6];
    const float* wp = (const float*)d_in[7];
    const float* bp = (const float*)d_in[8];
    const float* wf = (const float*)d_in[9];
    const float* bf = (const float*)d_in[10];

    float* out  = (float*)d_out;       // [1024*10]
    float* sel0 = out + 10240;         // [1024*8]
    float* loss = out + 18432;         // [1]
    float* mcnt = out + 18433;         // [8]

    float* ws_f = (float*)d_ws;
    float* ss   = ws_f;                 // 8192 floats
    float* gate = ws_f + 8192;          // 1024 floats
    int*   idx  = (int*)(ws_f + 9216);  // 1024 ints

    router_kernel<<<dim3(NB), dim3(256), 0, stream>>>(x, rw, rb, ss);
    solver_kernel<<<dim3(1), dim3(256), 0, stream>>>(ss, gate, idx, sel0, loss, mcnt);
    expert_kernel<<<dim3(NB), dim3(256), 0, stream>>>(x, w1, b1, wd, bd, wp, bp,
                                                      wf, bf, idx, gate, out);
}

// Round 15
// 132.594 us; speedup vs baseline: 1.0270x; 1.0270x over previous
//
#include <hip/hip_runtime.h>

#define NB 1024
#define NE 8

__device__ __forceinline__ float relu6f(float v) { return fminf(fmaxf(v, 0.0f), 6.0f); }

// ---- pure-DPP wave64 reductions ----
template <int CTRL>
__device__ __forceinline__ float dpp0(float x) {
    return __builtin_bit_cast(float,
        __builtin_amdgcn_update_dpp(0, __builtin_bit_cast(int, x), CTRL, 0xF, 0xF, false));
}
__device__ __forceinline__ float wmax63(float x) {   // nonneg inputs only
    x = fmaxf(x, dpp0<0x121>(x));
    x = fmaxf(x, dpp0<0x122>(x));
    x = fmaxf(x, dpp0<0x124>(x));
    x = fmaxf(x, dpp0<0x128>(x));
    x = fmaxf(x, dpp0<0x142>(x));
    x = fmaxf(x, dpp0<0x143>(x));
    return x;
}
__device__ __forceinline__ float wsum63(float x) {
    x += dpp0<0x121>(x);
    x += dpp0<0x122>(x);
    x += dpp0<0x124>(x);
    x += dpp0<0x128>(x);
    x += dpp0<0x142>(x);
    x += dpp0<0x143>(x);
    return x;
}

// HOT PATH: 8-value wave64 sum, fused v_add_f32_dpp, stage-major interleave
// (dependent ops 8 apart -> DPP hazard covered). Result valid in lanes 48..63.
#define DPP_ROW(OPND, CTRL) \
    "v_add_f32_dpp " OPND ", " OPND ", " OPND " " CTRL \
    " row_mask:0xf bank_mask:0xf bound_ctrl:0\n\t"
#define DPP_STAGE(CTRL) \
    DPP_ROW("%0", CTRL) DPP_ROW("%1", CTRL) DPP_ROW("%2", CTRL) DPP_ROW("%3", CTRL) \
    DPP_ROW("%4", CTRL) DPP_ROW("%5", CTRL) DPP_ROW("%6", CTRL) DPP_ROW("%7", CTRL)

__device__ __forceinline__ void wsum63x8(float p[8]) {
    asm volatile(
        "s_nop 1\n\t"
        DPP_STAGE("row_ror:1")
        DPP_STAGE("row_ror:2")
        DPP_STAGE("row_ror:4")
        DPP_STAGE("row_ror:8")
        DPP_STAGE("row_bcast:15")
        DPP_STAGE("row_bcast:31")
        : "+v"(p[0]), "+v"(p[1]), "+v"(p[2]), "+v"(p[3]),
          "+v"(p[4]), "+v"(p[5]), "+v"(p[6]), "+v"(p[7]));
}

// ---------------- Kernel A: router conv + softmax ----------------
__global__ __launch_bounds__(256) void router_kernel(
    const float* __restrict__ x, const float* __restrict__ rw,
    const float* __restrict__ rb, float* __restrict__ ss)
{
    __shared__ float rw_l[384];
    __shared__ float red[4][8];
    int b = blockIdx.x, t = threadIdx.x;
    for (int i = t; i < 384; i += 256) rw_l[i] = rw[i];
    __syncthreads();
    float acc[NE];
#pragma unroll
    for (int e = 0; e < NE; ++e) acc[e] = 0.f;
    const float* xb = x + b * 3072;
    for (int idx = t; idx < 3072; idx += 256) {
        float xv = xb[idx];
        int c = idx >> 10, rem = idx & 1023;
        int i = rem >> 5, j = rem & 31;
        int wb = c * 16 + (i & 3) * 4 + (j & 3);
#pragma unroll
        for (int e = 0; e < NE; ++e) acc[e] += xv * rw_l[e * 48 + wb];
    }
    wsum63x8(acc);
    int lane = t & 63, wave = t >> 6;
    if (lane == 63) {
#pragma unroll
        for (int e = 0; e < NE; ++e) red[wave][e] = acc[e];
    }
    __syncthreads();
    if (t == 0) {
        float s[NE], m = -1e30f;
#pragma unroll
        for (int e = 0; e < NE; ++e) {
            s[e] = red[0][e] + red[1][e] + red[2][e] + red[3][e] + rb[e];
            m = fmaxf(m, s[e]);
        }
        float xs = 0.f, ex[NE];
#pragma unroll
        for (int e = 0; e < NE; ++e) { ex[e] = expf(s[e] - m); xs += ex[e]; }
#pragma unroll
        for (int e = 0; e < NE; ++e) ss[b * 8 + e] = ex[e] / xs;
    }
}

// ---------------- Kernel B: OT solver (R11/R13 — at serial-latency floor) --
// 175 serial reduce->barrier->readback rounds ≈ 556cy each ≈ 97us; VALU 52%
// on the busy CU, rest is dependency stall. Verified model == measurement.
// G_n = I8; G_m == I (off-diag d~5400 -> exp underflows), so C_eff = C - pi.
__global__ __launch_bounds__(256, 2) void solver_kernel(
    const float* __restrict__ ss_g, float* __restrict__ gate_ws,
    int* __restrict__ idx_ws, float* __restrict__ sel0,
    float* __restrict__ loss_out, float* __restrict__ mcnt_out)
{
    __shared__ float sst[8192];                      // ss transposed: [e*1024+col]
    __shared__ __align__(16) float red[2][4][8];     // [parity][wave][e]
    __shared__ float redm[2][4];                     // [parity][wave] max partials
    __shared__ __align__(16) float cnt_sh[4][8], dp_sh[4][8];

    int t = threadIdx.x;
    int l = t & 63, w = t >> 6;

    float mx = 0.f;
    for (int i = t; i < 2048; i += 256) {
        float4 s4 = ((const float4*)ss_g)[i];
        int col = i >> 1, e0 = (i & 1) * 4;
        sst[(e0 + 0) * 1024 + col] = s4.x;
        sst[(e0 + 1) * 1024 + col] = s4.y;
        sst[(e0 + 2) * 1024 + col] = s4.z;
        sst[(e0 + 3) * 1024 + col] = s4.w;
        mx = fmaxf(mx, fmaxf(fmaxf(s4.x, s4.y), fmaxf(s4.z, s4.w)));
    }
    mx = wmax63(mx);
    if (l == 63) redm[0][w] = mx;
    __syncthreads();
    float gm = fmaxf(fmaxf(redm[0][0], redm[0][1]), fmaxf(redm[0][2], redm[0][3]));
    float ninv0 = -__builtin_amdgcn_rcpf(gm + 1e-9f);   // c = ss * ninv0

    int col0 = w * 256 + l;
    float c[4][8], k[4][8], v[4], u[8], p[8];
#pragma unroll
    for (int q = 0; q < 4; ++q) {
        v[q] = 1.f;
#pragma unroll
        for (int e = 0; e < 8; ++e) {
            c[q][e] = sst[e * 1024 + col0 + q * 64] * ninv0;  // once-scaled C
            k[q][e] = 1.f;
        }
    }
#pragma unroll
    for (int e = 0; e < 8; ++e) u[e] = 0.125f;   // u*k*v == pi0 == 0.125

    for (int outer = 0; outer < 25; ++outer) {
        int sm = (outer + 1) & 1;
        float lm = 0.f;
#pragma unroll
        for (int q = 0; q < 4; ++q)
#pragma unroll
            for (int e = 0; e < 8; ++e) {
                float ce = c[q][e] - u[e] * k[q][e] * v[q];
                k[q][e] = ce;
                lm = fmaxf(lm, fabsf(ce));
            }
        lm = wmax63(lm);
        if (l == 63) redm[sm][w] = lm;
        __syncthreads();
        float gmx = fmaxf(fmaxf(redm[sm][0], redm[sm][1]),
                          fmaxf(redm[sm][2], redm[sm][3]));
        float scl = -10.f * __builtin_amdgcn_rcpf(gmx + 1e-9f);  // -(1/sden)/LDA

        // exp pass fused with p0 = K @ 1
#pragma unroll
        for (int e = 0; e < 8; ++e) p[e] = 0.f;
#pragma unroll
        for (int q = 0; q < 4; ++q)
#pragma unroll
            for (int e = 0; e < 8; ++e) {
                float kk = __expf(k[q][e] * scl);
                k[q][e] = kk;
                p[e] += kk;
            }

        for (int it = 0; it < 6; ++it) {          // 5 full (u,v) + final u
            int s = it & 1;
            wsum63x8(p);
            if (l == 63) {
                *(float4*)&red[s][w][0] = make_float4(p[0], p[1], p[2], p[3]);
                *(float4*)&red[s][w][4] = make_float4(p[4], p[5], p[6], p[7]);
            }
            __syncthreads();
            float4 t00 = *(const float4*)&red[s][0][0];
            float4 t01 = *(const float4*)&red[s][0][4];
            float4 t10 = *(const float4*)&red[s][1][0];
            float4 t11 = *(const float4*)&red[s][1][4];
            float4 t20 = *(const float4*)&red[s][2][0];
            float4 t21 = *(const float4*)&red[s][2][4];
            float4 t30 = *(const float4*)&red[s][3][0];
            float4 t31 = *(const float4*)&red[s][3][4];
            u[0] = 128.f * __builtin_amdgcn_rcpf((t00.x + t10.x) + (t20.x + t30.x) + 1e-9f);
            u[1] = 128.f * __builtin_amdgcn_rcpf((t00.y + t10.y) + (t20.y + t30.y) + 1e-9f);
            u[2] = 128.f * __builtin_amdgcn_rcpf((t00.z + t10.z) + (t20.z + t30.z) + 1e-9f);
            u[3] = 128.f * __builtin_amdgcn_rcpf((t00.w + t10.w) + (t20.w + t30.w) + 1e-9f);
            u[4] = 128.f * __builtin_amdgcn_rcpf((t01.x + t11.x) + (t21.x + t31.x) + 1e-9f);
            u[5] = 128.f * __builtin_amdgcn_rcpf((t01.y + t11.y) + (t21.y + t31.y) + 1e-9f);
            u[6] = 128.f * __builtin_amdgcn_rcpf((t01.z + t11.z) + (t21.z + t31.z) + 1e-9f);
            u[7] = 128.f * __builtin_amdgcn_rcpf((t01.w + t11.w) + (t21.w + t31.w) + 1e-9f);
            if (it < 5) {
#pragma unroll
                for (int e = 0; e < 8; ++e) p[e] = 0.f;
#pragma unroll
                for (int q = 0; q < 4; ++q) {
                    float cs = 0.f;
#pragma unroll
                    for (int e = 0; e < 8; ++e) cs = fmaf(k[q][e], u[e], cs);
                    float vq = __builtin_amdgcn_rcpf(cs + 1e-9f);
                    v[q] = vq;
#pragma unroll
                    for (int e = 0; e < 8; ++e) p[e] = fmaf(k[q][e], vq, p[e]);
                }
            }
        }
    }

    // ---- epilogue: argmax / gate / select0 / counts / loss ----
    float cnt[8], dp[8];
#pragma unroll
    for (int e = 0; e < 8; ++e) { cnt[e] = 0.f; dp[e] = 0.f; }
#pragma unroll
    for (int q = 0; q < 4; ++q) {
        int col = col0 + q * 64;
        float pv[8];
#pragma unroll
        for (int e = 0; e < 8; ++e) pv[e] = u[e] * k[q][e] * v[q];
        int i = 0; float m = pv[0];
#pragma unroll
        for (int e = 1; e < 8; ++e) { if (pv[e] > m) { m = pv[e]; i = e; } }
        float g = 0.f;
        float se[8];
#pragma unroll
        for (int e = 0; e < 8; ++e) {
            float sv = sst[e * 1024 + col];
            dp[e] += sv;
            if (i == e) g = sv;
        }
#pragma unroll
        for (int e = 0; e < 8; ++e) {
            se[e] = (e == i && g != 0.f) ? 1.f : 0.f;
            cnt[e] += (e == i) ? 1.f : 0.f;
        }
        idx_ws[col] = i;
        gate_ws[col] = g;
        *(float4*)&sel0[col * 8]     = make_float4(se[0], se[1], se[2], se[3]);
        *(float4*)&sel0[col * 8 + 4] = make_float4(se[4], se[5], se[6], se[7]);
    }
#pragma unroll
    for (int e = 0; e < 8; ++e) { cnt[e] = wsum63(cnt[e]); dp[e] = wsum63(dp[e]); }
    if (l == 63) {
#pragma unroll
        for (int e = 0; e < 8; ++e) { cnt_sh[w][e] = cnt[e]; dp_sh[w][e] = dp[e]; }
    }
    __syncthreads();
    if (t == 0) {
        float loss = 0.f;
#pragma unroll
        for (int e = 0; e < 8; ++e) {
            float ce2 = cnt_sh[0][e] + cnt_sh[1][e] + cnt_sh[2][e] + cnt_sh[3][e];
            float de2 = dp_sh[0][e] + dp_sh[1][e] + dp_sh[2][e] + dp_sh[3][e];
            loss += (de2 * (1.f / 1024.f)) * (ce2 * (1.f / 1024.f));
            mcnt_out[e] = ce2;
        }
        loss_out[0] = loss * 8.f;
    }
}

// ---------------- Kernel C: per-sample fused expert forward (R13 exact) ----
// R14 lesson: stride-36 b128 vectorization was neutral-to-negative (4-way
// row aliasing ate the issue savings) -> byte-exact revert to R13 (133.0us).
__global__ __launch_bounds__(256, 2) void expert_kernel(
    const float* __restrict__ x,
    const float* __restrict__ w1g, const float* __restrict__ b1g,
    const float* __restrict__ wdg, const float* __restrict__ bdg,
    const float* __restrict__ wpg, const float* __restrict__ bpg,
    const float* __restrict__ wfg, const float* __restrict__ bfg,
    const int* __restrict__ idx_ws, const float* __restrict__ gate_ws,
    float* __restrict__ out)
{
    __shared__ float xl[3][34][35];
    __shared__ float h1[8][33][33];   // 8-channel group; row/col 32 zeroed
    __shared__ __align__(16) float h2q[4][256][4];   // [c>>2][point][c&3]
    __shared__ float w1_l[432];
    __shared__ float wd_l[144];
    __shared__ float wp_l[512];
    __shared__ float wf_l[320];
    __shared__ float b1_l[16], bd_l[16], bp_l[32], bf_l[10];
    __shared__ __align__(16) float pooled[32];

    int b = blockIdx.x, t = threadIdx.x;
    int l = t & 63;
    int e = idx_ws[b];
    float gate = gate_ws[b];

    float* xz = &xl[0][0][0];
    for (int i = t; i < 3 * 34 * 35; i += 256) xz[i] = 0.f;
    for (int i = t; i < 432; i += 256) w1_l[i] = w1g[e * 432 + i];
    if (t < 144) wd_l[t] = wdg[e * 144 + t];
    for (int i = t; i < 512; i += 256) wp_l[i] = wpg[e * 512 + i];
    for (int i = t; i < 320; i += 256) wf_l[i] = wfg[e * 320 + i];
    if (t < 16) b1_l[t] = b1g[e * 16 + t];
    if (t < 16) bd_l[t] = bdg[e * 16 + t];
    if (t < 32) bp_l[t] = bpg[e * 32 + t];
    if (t < 10) bf_l[t] = bfg[e * 10 + t];
    __syncthreads();
    const float* xb = x + b * 3072;
    for (int i = t; i < 3072; i += 256) {
        int c = i >> 10, r = (i >> 5) & 31, j = i & 31;
        xl[c][r + 1][j + 1] = xb[i];
    }
    __syncthreads();

    int ocl = t >> 6;
    int rr = (t >> 1) & 31;
    int jh = t & 1;

    for (int g = 0; g < 2; ++g) {
        int oc0 = g * 8 + ocl * 2;
        float acc[2][16];
#pragma unroll
        for (int kk = 0; kk < 16; ++kk) { acc[0][kk] = b1_l[oc0]; acc[1][kk] = b1_l[oc0 + 1]; }
#pragma unroll
        for (int c = 0; c < 3; ++c) {
#pragma unroll
            for (int di = 0; di < 3; ++di) {
                const float* xr = &xl[c][rr + di][jh * 16];
                float xreg[18];
#pragma unroll
                for (int kk = 0; kk < 18; ++kk) xreg[kk] = xr[kk];
#pragma unroll
                for (int dj = 0; dj < 3; ++dj) {
                    float w0 = w1_l[oc0 * 27 + c * 9 + di * 3 + dj];
                    float w1 = w1_l[(oc0 + 1) * 27 + c * 9 + di * 3 + dj];
#pragma unroll
                    for (int kk = 0; kk < 16; ++kk) {
                        acc[0][kk] = fmaf(xreg[kk + dj], w0, acc[0][kk]);
                        acc[1][kk] = fmaf(xreg[kk + dj], w1, acc[1][kk]);
                    }
                }
            }
        }
        int lc0 = ocl * 2;
#pragma unroll
        for (int kk = 0; kk < 16; ++kk) {
            h1[lc0][rr][jh * 16 + kk]     = relu6f(acc[0][kk]);
            h1[lc0 + 1][rr][jh * 16 + kk] = relu6f(acc[1][kk]);
        }
        if (t < 256) { int cc = t / 33, kk = t % 33; if (cc < 8) h1[cc][32][kk] = 0.f; }
        if (t < 8)   { h1[7][32][t + 25] = 0.f; }
        h1[t >> 5][t & 31][32] = 0.f;
        __syncthreads();
        int i2 = t >> 4, j2 = t & 15;
        float dwa[8];
#pragma unroll
        for (int q = 0; q < 8; ++q) {
            float a = bd_l[g * 8 + q];
#pragma unroll
            for (int di = 0; di < 3; ++di) {
#pragma unroll
                for (int dj = 0; dj < 3; ++dj)
                    a = fmaf(h1[q][2 * i2 + di][2 * j2 + dj],
                             wd_l[(g * 8 + q) * 9 + di * 3 + dj], a);
            }
            dwa[q] = relu6f(a);
        }
        *(float4*)&h2q[g * 2 + 0][t][0] = make_float4(dwa[0], dwa[1], dwa[2], dwa[3]);
        *(float4*)&h2q[g * 2 + 1][t][0] = make_float4(dwa[4], dwa[5], dwa[6], dwa[7]);
        __syncthreads();
    }

    // pointwise 16->32 (+bp, relu6) + pool: wave=8 oc, lane=4 pts (stride 64)
    {
        int ocg = t >> 6;
        int pg  = t & 63;
        float hv[4][16];
#pragma unroll
        for (int pt = 0; pt < 4; ++pt) {
            int pp = pg + pt * 64;
            float4 q0 = *(const float4*)&h2q[0][pp][0];
            float4 q1 = *(const float4*)&h2q[1][pp][0];
            float4 q2 = *(const float4*)&h2q[2][pp][0];
            float4 q3 = *(const float4*)&h2q[3][pp][0];
            hv[pt][0] = q0.x;  hv[pt][1] = q0.y;  hv[pt][2] = q0.z;  hv[pt][3] = q0.w;
            hv[pt][4] = q1.x;  hv[pt][5] = q1.y;  hv[pt][6] = q1.z;  hv[pt][7] = q1.w;
            hv[pt][8] = q2.x;  hv[pt][9] = q2.y;  hv[pt][10] = q2.z; hv[pt][11] = q2.w;
            hv[pt][12] = q3.x; hv[pt][13] = q3.y; hv[pt][14] = q3.z; hv[pt][15] = q3.w;
        }
        float pool[8];
#pragma unroll
        for (int o = 0; o < 8; ++o) {
            int oc = ocg * 8 + o;
            float a0 = bp_l[oc], a1 = a0, a2 = a0, a3 = a0;
#pragma unroll
            for (int c = 0; c < 16; ++c) {
                float wv = wp_l[oc * 16 + c];
                a0 = fmaf(hv[0][c], wv, a0);
                a1 = fmaf(hv[1][c], wv, a1);
                a2 = fmaf(hv[2][c], wv, a2);
                a3 = fmaf(hv[3][c], wv, a3);
            }
            pool[o] = (relu6f(a0) + relu6f(a1)) + (relu6f(a2) + relu6f(a3));
        }
        wsum63x8(pool);
        if (l == 63) {
            *(float4*)&pooled[ocg * 8]     = make_float4(pool[0], pool[1], pool[2], pool[3]);
            *(float4*)&pooled[ocg * 8 + 4] = make_float4(pool[4], pool[5], pool[6], pool[7]);
        }
    }
    __syncthreads();
    if (t < 10) {
        float o = bf_l[t];
#pragma unroll
        for (int c = 0; c < 32; ++c)
            o = fmaf(pooled[c] * (1.0f / 256.0f), wf_l[t * 32 + c], o);
        out[b * 10 + t] = gate * o;
    }
}

extern "C" void kernel_launch(void* const* d_in, const int* in_sizes, int n_in,
                              void* d_out, int out_size, void* d_ws, size_t ws_size,
                              hipStream_t stream) {
    const float* x  = (const float*)d_in[0];
    const float* rw = (const float*)d_in[1];
    const float* rb = (const float*)d_in[2];
    const float* w1 = (const float*)d_in[3];
    const float* b1 = (const float*)d_in[4];
    const float* wd = (const float*)d_in[5];
    const float* bd = (const float*)d_in[6];
    const float* wp = (const float*)d_in[7];
    const float* bp = (const float*)d_in[8];
    const float* wf = (const float*)d_in[9];
    const float* bf = (const float*)d_in[10];

    float* out  = (float*)d_out;       // [1024*10]
    float* sel0 = out + 10240;         // [1024*8]
    float* loss = out + 18432;         // [1]
    float* mcnt = out + 18433;         // [8]

    float* ws_f = (float*)d_ws;
    float* ss   = ws_f;                 // 8192 floats
    float* gate = ws_f + 8192;          // 1024 floats
    int*   idx  = (int*)(ws_f + 9216);  // 1024 ints

    router_kernel<<<dim3(NB), dim3(256), 0, stream>>>(x, rw, rb, ss);
    solver_kernel<<<dim3(1), dim3(256), 0, stream>>>(ss, gate, idx, sel0, loss, mcnt);
    expert_kernel<<<dim3(NB), dim3(256), 0, stream>>>(x, w1, b1, wd, bd, wp, bp,
                                                      wf, bf, idx, gate, out);
}